// Round 22
// baseline (46.498 us; speedup 1.0000x reference)
//
#include <hip/hip_runtime.h>

// LocallyConnectedGC: out[bt, m] = sum_n x[bt, n] * (S*W)[n, m] + b[m]
// S = band mask, half-width 4, ring of 208 -> 9 weights per output column.
//
// R20 = R17 skeleton + FUSED d-loop (band read once per 2 rows).
//  Evidence: R12 best (42.7us) pays 12 ds_read_b128/row (9 band + 3 x)
//  ~60K cyc/CU. R19 (AGPR band) proved conflicts (5.0M) are from x reads
//  + staging DMA, NOT band reads, and that volatile AREADs serialize VALU.
//  R17 (2 rows/thread) failed only because its two ROWCOMP d-loops each
//  re-read the band. Here ONE d-loop: bd loaded once, feeds both rows'
//  FMAs immediately -> 15 reads per 2 rows (7.5/row, -37% vs R12).
//  - TR=32, 832 threads, 2 gload_lds/thread/stage, 2 LDS buffers,
//    exact counted vmcnt (2/4) + raw s_barrier. R17-verbatim, passed.

#define NN   208
#define NC   52          // NN/4 float4 chunks per row
#define HW   4
#define BAND 9
#define TR   32          // rows per tile
#define THREADS 832      // 13 waves; thread = (chunk c, rows rg, rg+16)
#define NBLK 512
#define TILE_F  (TR * NN)     // 6656 floats per tile

typedef float vfloat4 __attribute__((ext_vector_type(4)));

__global__ __launch_bounds__(THREADS) void lcgc_kernel(
    const float* __restrict__ x,
    const float* __restrict__ W,
    const float* __restrict__ b,
    const float* __restrict__ S,
    float* __restrict__ out,
    int total_rows)
{
    __shared__ float sX[2][TILE_F];      // 53.2 KB double-buffered x tile
    __shared__ float sBand[BAND * NN];   // 7.5 KB masked weight band
    __shared__ float sBias[NN];

    const int tid = threadIdx.x;

    // One-time cooperative band+bias build (coalesced; W/S/b L2-hot).
    for (int i = tid; i < BAND * NN; i += THREADS) {
        int d = i / NN;
        int m = i - d * NN;
        int n = m + d - HW;
        if (n < 0) n += NN;
        else if (n >= NN) n -= NN;
        sBand[i] = W[n * NN + m] * S[n * NN + m];
    }
    if (tid < NN) sBias[tid] = b[tid];
    __syncthreads();   // drains ALL prior vmem: queue now stages/stores only

    const int c    = tid % NC;           // fixed column chunk
    const int rg   = tid / NC;           // row within tile, 0..15 (+16 pair)
    const int wave = tid >> 6;

    const int cm = (c == 0)      ? NC - 1 : c - 1;
    const int cp = (c == NC - 1) ? 0      : c + 1;

    const long long ntiles_total = total_rows / TR;          // 4096
    const long long nt = ntiles_total / gridDim.x;           // 8 (runtime)
    const long long t0 = (long long)blockIdx.x * nt;

    // Wave-uniform LDS staging bases (HW writes base + lane*16).
    float* const ldswA = &sX[0][wave * 256];          // float4 64w..64w+63
    float* const ldswB = &sX[0][3328 + wave * 256];   // float4 832+64w..

    #define STAGE(kt)                                                         \
        do {                                                                  \
            const long long base = (t0 + (kt)) * TILE_F;                      \
            const int bo = (int)((kt) & 1) * TILE_F;                          \
            __builtin_amdgcn_global_load_lds(                                 \
                (const __attribute__((address_space(1))) void*)               \
                    (x + base + (long long)tid * 4),                          \
                (__attribute__((address_space(3))) void*)(ldswA + bo),        \
                16, 0, 0);                                                    \
            __builtin_amdgcn_global_load_lds(                                 \
                (const __attribute__((address_space(1))) void*)               \
                    (x + base + 3328 + (long long)tid * 4),                   \
                (__attribute__((address_space(3))) void*)(ldswB + bo),        \
                16, 0, 0);                                                    \
        } while (0)

    #define COMPUTE(kt)                                                       \
        do {                                                                  \
            const int bi = (int)((kt) & 1);                                   \
            const float4* band4 = reinterpret_cast<const float4*>(sBand);     \
            const float4 bias4 =                                              \
                *reinterpret_cast<const float4*>(&sBias[c * 4]);              \
            const float4* xr4a =                                              \
                reinterpret_cast<const float4*>(&sX[bi][rg * NN]);            \
            const float4* xr4b =                                              \
                reinterpret_cast<const float4*>(&sX[bi][(rg + 16) * NN]);     \
            const float4 aL0 = xr4a[cm], aC0 = xr4a[c], aR0 = xr4a[cp];       \
            const float4 aL1 = xr4b[cm], aC1 = xr4b[c], aR1 = xr4b[cp];       \
            const float xv0[12] = {aL0.x, aL0.y, aL0.z, aL0.w,                \
                                   aC0.x, aC0.y, aC0.z, aC0.w,                \
                                   aR0.x, aR0.y, aR0.z, aR0.w};               \
            const float xv1[12] = {aL1.x, aL1.y, aL1.z, aL1.w,                \
                                   aC1.x, aC1.y, aC1.z, aC1.w,                \
                                   aR1.x, aR1.y, aR1.z, aR1.w};               \
            float4 acc0 = bias4;                                              \
            float4 acc1 = bias4;                                              \
            _Pragma("unroll")                                                 \
            for (int d = 0; d < BAND; ++d) {                                  \
                const float4 bd = band4[d * NC + c];  /* ONE read, 2 rows */  \
                acc0.x = fmaf(bd.x, xv0[0 + d], acc0.x);                      \
                acc0.y = fmaf(bd.y, xv0[1 + d], acc0.y);                      \
                acc0.z = fmaf(bd.z, xv0[2 + d], acc0.z);                      \
                acc0.w = fmaf(bd.w, xv0[3 + d], acc0.w);                      \
                acc1.x = fmaf(bd.x, xv1[0 + d], acc1.x);                      \
                acc1.y = fmaf(bd.y, xv1[1 + d], acc1.y);                      \
                acc1.z = fmaf(bd.z, xv1[2 + d], acc1.z);                      \
                acc1.w = fmaf(bd.w, xv1[3 + d], acc1.w);                      \
            }                                                                 \
            const long long grow = (t0 + (kt)) * TR + rg;                     \
            vfloat4 av0 = {acc0.x, acc0.y, acc0.z, acc0.w};                   \
            vfloat4 av1 = {acc1.x, acc1.y, acc1.z, acc1.w};                   \
            __builtin_nontemporal_store(av0, reinterpret_cast<vfloat4*>(      \
                out + grow * NN + c * 4));                                    \
            __builtin_nontemporal_store(av1, reinterpret_cast<vfloat4*>(      \
                out + (grow + 16) * NN + c * 4));                             \
        } while (0)

    // Prologue: stage tile 0 into buffer 0.
    STAGE(0);

    for (long long k = 0; k < nt; ++k) {
        if (k + 1 < nt) STAGE(k + 1);
        // Exact in-order count: queue = stage_k(2) [, stores_{k-1}(2)]
        // [, stage_{k+1}(2)]. Complete stage_k, leave the rest in flight.
        {
            const int nv = (k >= 1 ? 2 : 0) + (k + 1 < nt ? 2 : 0);
            switch (nv) {
            case 0: asm volatile("s_waitcnt vmcnt(0)" ::: "memory"); break;
            case 2: asm volatile("s_waitcnt vmcnt(2)" ::: "memory"); break;
            default: asm volatile("s_waitcnt vmcnt(4)" ::: "memory"); break;
            }
        }
        __builtin_amdgcn_sched_barrier(0);
        __builtin_amdgcn_s_barrier();      // all waves' tile-k data visible
        COMPUTE(k);
        asm volatile("" ::: "memory");
        __builtin_amdgcn_s_barrier();      // reads of buf k&1 done before
                                           // iter k+1 restages it
    }

    #undef STAGE
    #undef COMPUTE
}

extern "C" void kernel_launch(void* const* d_in, const int* in_sizes, int n_in,
                              void* d_out, int out_size, void* d_ws, size_t ws_size,
                              hipStream_t stream) {
    const float* x = (const float*)d_in[0];
    const float* W = (const float*)d_in[1];
    const float* b = (const float*)d_in[2];
    const float* S = (const float*)d_in[3];
    float* out = (float*)d_out;

    const int total_rows = in_sizes[0] / NN;   // 131072 = 4096 tiles of 32
    lcgc_kernel<<<dim3(NBLK), dim3(THREADS), 0, stream>>>(
        x, W, b, S, out, total_rows);
}